// Round 6
// baseline (222.612 us; speedup 1.0000x reference)
//
#include <hip/hip_runtime.h>
#include <hip/hip_bf16.h>
#include <cstdint>

#define HH 4
#define CC 64
#define KDIM 256   // IN_CH
#define NOUT 256   // H*C
#define BM 128
#define BN 64
#define BK 64

typedef __attribute__((ext_vector_type(8))) short bf16x8;
typedef __attribute__((ext_vector_type(4))) float f32x4;
typedef unsigned short ushort_t;

__device__ __forceinline__ unsigned short f2bf(float f) {
  unsigned u = __float_as_uint(f);
  unsigned r = (u + 0x7fff + ((u >> 16) & 1)) >> 16;  // RNE
  return (unsigned short)r;
}

__device__ __forceinline__ unsigned pk2bf(float lo, float hi) {
  return (unsigned)f2bf(lo) | ((unsigned)f2bf(hi) << 16);
}

// ---------------- degree count ----------------
__global__ __launch_bounds__(256)
void deg_count(const int* __restrict__ ei, int* __restrict__ deg, int E) {
  int t = blockIdx.x * 256 + threadIdx.x;
  if (t < E) atomicAdd(&deg[ei[E + t]], 1);
}

// ---------------- MFMA GEMM: Wh(bf16) = x @ W^T  (fp32 in, reg-staged cvt) ----------------
// Block covers BN=64 cols == exactly one head h = col0>>6. Fused attention scores.
__global__ __launch_bounds__(256)
void gemm_bf16(const float* __restrict__ X, const float* __restrict__ W,
               ushort_t* __restrict__ Wh, float* __restrict__ s_src,
               float* __restrict__ s_dst, const float* __restrict__ att, int M) {
  __shared__ char lds[(BM + BN) * BK * 2];  // A: 16KB bf16, B: 8KB bf16
  const int tid = threadIdx.x;
  const int lane = tid & 63;
  const int w = tid >> 6;
  const int row0 = blockIdx.y * BM;
  const int col0 = blockIdx.x * BN;
  char* As = lds;
  char* Bs = lds + BM * BK * 2;

  // staging coords
  const int ar = tid >> 1;            // 0..127  (A row)
  const int aq0 = (tid & 1) * 4;      // first 8-elem group (of 8 per row)
  const int br = tid >> 2;            // 0..63   (B row)
  const int bq0 = (tid & 3) * 2;      // first 8-elem group

  f32x4 acc[2][4] = {};

  for (int k0 = 0; k0 < KDIM; k0 += BK) {
    // ---- stage A: 128x64 fp32 -> bf16, XOR-swizzled groups ----
    {
      const bool val = (row0 + ar) < M;
      const float* gx = X + (size_t)(row0 + ar) * KDIM + k0 + aq0 * 8;
      float4 f[8];
#pragma unroll
      for (int i = 0; i < 8; ++i)
        f[i] = val ? *(const float4*)(gx + i * 4) : make_float4(0.f, 0.f, 0.f, 0.f);
#pragma unroll
      for (int i = 0; i < 4; ++i) {
        int q = aq0 + i;
        int phys = q ^ (ar & 7);
        uint4 o;
        o.x = pk2bf(f[2 * i].x, f[2 * i].y);
        o.y = pk2bf(f[2 * i].z, f[2 * i].w);
        o.z = pk2bf(f[2 * i + 1].x, f[2 * i + 1].y);
        o.w = pk2bf(f[2 * i + 1].z, f[2 * i + 1].w);
        *(uint4*)(As + (ar * 8 + phys) * 16) = o;
      }
    }
    // ---- stage B: 64x64 fp32 -> bf16 ----
    {
      const float* gw = W + (size_t)(col0 + br) * KDIM + k0 + bq0 * 8;
      float4 g[4];
#pragma unroll
      for (int i = 0; i < 4; ++i) g[i] = *(const float4*)(gw + i * 4);
#pragma unroll
      for (int i = 0; i < 2; ++i) {
        int q = bq0 + i;
        int phys = q ^ (br & 7);
        uint4 o;
        o.x = pk2bf(g[2 * i].x, g[2 * i].y);
        o.y = pk2bf(g[2 * i].z, g[2 * i].w);
        o.z = pk2bf(g[2 * i + 1].x, g[2 * i + 1].y);
        o.w = pk2bf(g[2 * i + 1].z, g[2 * i + 1].w);
        *(uint4*)(Bs + (br * 8 + phys) * 16) = o;
      }
    }
    __syncthreads();

#pragma unroll
    for (int kk = 0; kk < 2; ++kk) {
      bf16x8 aF[2], bF[4];
#pragma unroll
      for (int rt = 0; rt < 2; ++rt) {
        int r = w * 32 + rt * 16 + (lane & 15);
        int qq = kk * 4 + (lane >> 4);
        int phys = qq ^ (r & 7);
        aF[rt] = *(const bf16x8*)(As + r * 128 + phys * 16);
      }
#pragma unroll
      for (int ct = 0; ct < 4; ++ct) {
        int cl = ct * 16 + (lane & 15);
        int qq = kk * 4 + (lane >> 4);
        int phys = qq ^ (cl & 7);
        bF[ct] = *(const bf16x8*)(Bs + cl * 128 + phys * 16);
      }
#pragma unroll
      for (int rt = 0; rt < 2; ++rt)
#pragma unroll
        for (int ct = 0; ct < 4; ++ct)
          acc[rt][ct] = __builtin_amdgcn_mfma_f32_16x16x32_bf16(aF[rt], bF[ct], acc[rt][ct], 0, 0, 0);
    }
    __syncthreads();
  }

  // ---- fused per-node attention scores for head h = col0>>6 ----
  const int h = col0 >> 6;
  float att_s[4], att_d[4];
#pragma unroll
  for (int ct = 0; ct < 4; ++ct) {
    att_s[ct] = att[h * 2 * CC + ct * 16 + (lane & 15)];
    att_d[ct] = att[h * 2 * CC + CC + ct * 16 + (lane & 15)];
  }
#pragma unroll
  for (int rt = 0; rt < 2; ++rt) {
#pragma unroll
    for (int reg = 0; reg < 4; ++reg) {
      float ls = 0.f, ld_ = 0.f;
#pragma unroll
      for (int ct = 0; ct < 4; ++ct) {
        float a = acc[rt][ct][reg];
        ls += a * att_s[ct];
        ld_ += a * att_d[ct];
      }
#pragma unroll
      for (int off = 1; off < 16; off <<= 1) {
        ls += __shfl_xor(ls, off);
        ld_ += __shfl_xor(ld_, off);
      }
      int r = row0 + w * 32 + rt * 16 + (lane >> 4) * 4 + reg;
      if ((lane & 15) == 0 && r < M) {
        s_src[r * HH + h] = ls;
        s_dst[r * HH + h] = ld_;
      }
    }
  }

  // ---- Wh store (m89 layout: col=lane&15, row=(lane>>4)*4+reg) ----
#pragma unroll
  for (int rt = 0; rt < 2; ++rt) {
#pragma unroll
    for (int reg = 0; reg < 4; ++reg) {
      int r = row0 + w * 32 + rt * 16 + (lane >> 4) * 4 + reg;
      if (r < M) {
#pragma unroll
        for (int ct = 0; ct < 4; ++ct) {
          int ccol = col0 + ct * 16 + (lane & 15);
          Wh[(size_t)r * NOUT + ccol] = f2bf(acc[rt][ct][reg]);
        }
      }
    }
  }
}

// ---------------- scan (3 kernels) ----------------
__global__ void scan_partial(const int* __restrict__ deg, int* __restrict__ bsums, int N) {
  __shared__ int sd[256];
  int i = blockIdx.x * 256 + threadIdx.x;
  sd[threadIdx.x] = (i < N) ? deg[i] : 0;
  __syncthreads();
  for (int s = 128; s > 0; s >>= 1) {
    if (threadIdx.x < s) sd[threadIdx.x] += sd[threadIdx.x + s];
    __syncthreads();
  }
  if (threadIdx.x == 0) bsums[blockIdx.x] = sd[0];
}

__global__ void scan_bsums(int* __restrict__ bsums, int NB) {
  __shared__ int sd[256];
  int t = threadIdx.x;
  int v = (t < NB) ? bsums[t] : 0;
  sd[t] = v;
  __syncthreads();
  for (int off = 1; off < 256; off <<= 1) {
    int add = (t >= off) ? sd[t - off] : 0;
    __syncthreads();
    sd[t] += add;
    __syncthreads();
  }
  bsums[t] = sd[t] - v;  // exclusive
}

__global__ void scan_final(const int* __restrict__ deg, const int* __restrict__ bsums,
                           int* __restrict__ row_ptr, int* __restrict__ cursor, int N) {
  __shared__ int sd[256];
  int t = threadIdx.x;
  int i = blockIdx.x * 256 + t;
  int v = (i < N) ? deg[i] : 0;
  sd[t] = v;
  __syncthreads();
  for (int off = 1; off < 256; off <<= 1) {
    int add = (t >= off) ? sd[t - off] : 0;
    __syncthreads();
    sd[t] += add;
    __syncthreads();
  }
  int excl = sd[t] - v + bsums[blockIdx.x];
  if (i < N) { row_ptr[i] = excl; cursor[i] = excl; }
  if (i == N - 1) row_ptr[N] = excl + v;
}

// ---------------- CSR scatter (indices only) ----------------
__global__ __launch_bounds__(256)
void csr_scatter(const int* __restrict__ ei, int* __restrict__ cursor,
                 int* __restrict__ csr_src, int E) {
  int t = blockIdx.x * 256 + threadIdx.x;
  if (t >= E) return;
  int s = ei[t];
  int d = ei[E + t];
  int pos = atomicAdd(&cursor[d], 1);
  csr_src[pos] = s;
}

// ---------------- aggregation: inline p=exp(leaky(.)), 4-deep MLP, fused ELU ----------------
__global__ __launch_bounds__(256)
void aggregate(const ushort_t* __restrict__ Wh, const float* __restrict__ s_src,
               const float* __restrict__ s_dst, const int* __restrict__ row_ptr,
               const int* __restrict__ csr_src, float* __restrict__ out, int N) {
  int wid = (int)((blockIdx.x * 256 + threadIdx.x) >> 6);
  int lane = threadIdx.x & 63;
  if (wid >= N) return;
  int half = lane >> 5, cl = lane & 31;
  int h = cl >> 3;
  int start = row_ptr[wid], end = row_ptr[wid + 1];
  float sd = s_dst[wid * HH + h];
  float acc[8] = {};
  float dsum = 0.f;
  int idx = start + half;
  // 4 edges in flight per half (8 per wave)
  for (; idx + 6 < end; idx += 8) {
    int s[4];
#pragma unroll
    for (int k = 0; k < 4; ++k) s[k] = csr_src[idx + 2 * k];
    float p[4];
    uint4 wv[4];
#pragma unroll
    for (int k = 0; k < 4; ++k) {
      float v = s_src[s[k] * HH + h] + sd;
      v = v > 0.f ? v : 0.2f * v;
      p[k] = __expf(v);
      wv[k] = *(const uint4*)(Wh + (size_t)s[k] * NOUT + cl * 8);
    }
#pragma unroll
    for (int k = 0; k < 4; ++k) {
      dsum += p[k];
#pragma unroll
      for (int j = 0; j < 4; ++j) {
        unsigned u = ((const unsigned*)&wv[k])[j];
        acc[2 * j]     += p[k] * __uint_as_float(u << 16);
        acc[2 * j + 1] += p[k] * __uint_as_float(u & 0xffff0000u);
      }
    }
  }
  for (; idx < end; idx += 2) {
    int s0 = csr_src[idx];
    float v = s_src[s0 * HH + h] + sd;
    v = v > 0.f ? v : 0.2f * v;
    float p0 = __expf(v);
    uint4 w0 = *(const uint4*)(Wh + (size_t)s0 * NOUT + cl * 8);
    dsum += p0;
#pragma unroll
    for (int j = 0; j < 4; ++j) {
      unsigned u0 = ((const unsigned*)&w0)[j];
      acc[2 * j]     += p0 * __uint_as_float(u0 << 16);
      acc[2 * j + 1] += p0 * __uint_as_float(u0 & 0xffff0000u);
    }
  }
#pragma unroll
  for (int j = 0; j < 8; ++j) acc[j] += __shfl_xor(acc[j], 32);
  dsum += __shfl_xor(dsum, 32);
  if (half == 0) {
    float rd = 1.0f / (dsum + 1e-16f);
    float o[8];
#pragma unroll
    for (int j = 0; j < 8; ++j) {
      float a = acc[j] * rd;
      o[j] = a > 0.f ? a : expm1f(a);
    }
    float* op = out + (size_t)wid * NOUT + cl * 8;
    *(float4*)op = make_float4(o[0], o[1], o[2], o[3]);
    *(float4*)(op + 4) = make_float4(o[4], o[5], o[6], o[7]);
  }
}

extern "C" void kernel_launch(void* const* d_in, const int* in_sizes, int n_in,
                              void* d_out, int out_size, void* d_ws, size_t ws_size,
                              hipStream_t stream) {
  const float* x = (const float*)d_in[0];
  const int* ei = (const int*)d_in[1];
  const float* W = (const float*)d_in[2];
  const float* att = (const float*)d_in[3];
  float* out = (float*)d_out;
  const int N = in_sizes[0] / KDIM;
  const int E = in_sizes[1] / 2;
  const int NPAD = ((N + BM - 1) / BM) * BM;

  char* p = (char*)d_ws;
  auto alloc = [&](size_t bytes) {
    char* r = p;
    p += (bytes + 255) & ~(size_t)255;
    return r;
  };
  ushort_t* Wh   = (ushort_t*)alloc((size_t)NPAD * NOUT * 2);
  float* s_src   = (float*)alloc((size_t)N * HH * 4);
  float* s_dst   = (float*)alloc((size_t)N * HH * 4);
  int* deg       = (int*)alloc((size_t)N * 4);
  int* row_ptr   = (int*)alloc((size_t)(N + 1) * 4);
  int* cursor    = (int*)alloc((size_t)N * 4);
  int* bsums     = (int*)alloc(256 * 4);
  int* csr_src   = (int*)alloc((size_t)E * 4);

  (void)hipMemsetAsync(deg, 0, (size_t)N * 4, stream);

  int eblocks = (E + 255) / 256;
  deg_count<<<eblocks, 256, 0, stream>>>(ei, deg, E);

  int NB = (N + 255) / 256;
  scan_partial<<<NB, 256, 0, stream>>>(deg, bsums, N);
  scan_bsums<<<1, 256, 0, stream>>>(bsums, NB);
  scan_final<<<NB, 256, 0, stream>>>(deg, bsums, row_ptr, cursor, N);

  csr_scatter<<<eblocks, 256, 0, stream>>>(ei, cursor, csr_src, E);

  dim3 gg(NOUT / BN, NPAD / BM);
  gemm_bf16<<<gg, 256, 0, stream>>>(x, W, Wh, s_src, s_dst, att, N);

  aggregate<<<(N + 3) / 4, 256, 0, stream>>>(Wh, s_src, s_dst, row_ptr, csr_src, out, N);
}

// Round 7
// 210.256 us; speedup vs baseline: 1.0588x; 1.0588x over previous
//
#include <hip/hip_runtime.h>
#include <hip/hip_bf16.h>
#include <cstdint>

#define HH 4
#define CC 64
#define KDIM 256   // IN_CH
#define NOUT 256   // H*C
#define BM 128
#define BN 64
#define BK 64

typedef __attribute__((ext_vector_type(8))) short bf16x8;
typedef __attribute__((ext_vector_type(4))) float f32x4;
typedef unsigned short ushort_t;

__device__ __forceinline__ unsigned short f2bf(float f) {
  unsigned u = __float_as_uint(f);
  unsigned r = (u + 0x7fff + ((u >> 16) & 1)) >> 16;  // RNE
  return (unsigned short)r;
}

// ---------------- fused: convert x,W to bf16 (+pad) AND degree count ----------------
__global__ __launch_bounds__(256)
void convert_and_deg(const float* __restrict__ x, const float* __restrict__ W,
                     ushort_t* __restrict__ xb, ushort_t* __restrict__ Wb,
                     const int* __restrict__ ei, int* __restrict__ deg,
                     long long NK, long long NPK, long long WK, int cblocks, int E) {
  if ((int)blockIdx.x < cblocks) {
    long long i = ((long long)blockIdx.x * 256 + threadIdx.x) * 8;
    if (i < NPK) {
      uint4 o = make_uint4(0u, 0u, 0u, 0u);
      if (i < NK) {
        float4 a = *(const float4*)(x + i);
        float4 b = *(const float4*)(x + i + 4);
        o.x = (unsigned)f2bf(a.x) | ((unsigned)f2bf(a.y) << 16);
        o.y = (unsigned)f2bf(a.z) | ((unsigned)f2bf(a.w) << 16);
        o.z = (unsigned)f2bf(b.x) | ((unsigned)f2bf(b.y) << 16);
        o.w = (unsigned)f2bf(b.z) | ((unsigned)f2bf(b.w) << 16);
      }
      *(uint4*)(xb + i) = o;
    } else {
      long long j = i - NPK;
      if (j < WK) {
        float4 a = *(const float4*)(W + j);
        float4 b = *(const float4*)(W + j + 4);
        uint4 o;
        o.x = (unsigned)f2bf(a.x) | ((unsigned)f2bf(a.y) << 16);
        o.y = (unsigned)f2bf(a.z) | ((unsigned)f2bf(a.w) << 16);
        o.z = (unsigned)f2bf(b.x) | ((unsigned)f2bf(b.y) << 16);
        o.w = (unsigned)f2bf(b.z) | ((unsigned)f2bf(b.w) << 16);
        *(uint4*)(Wb + j) = o;
      }
    }
  } else {
    int t = ((int)blockIdx.x - cblocks) * 256 + threadIdx.x;
    if (t < E) atomicAdd(&deg[ei[E + t]], 1);
  }
}

// ---------------- scan step 1: per-block sums ----------------
__global__ void scan_partial(const int* __restrict__ deg, int* __restrict__ bsums, int N) {
  __shared__ int sd[256];
  int i = blockIdx.x * 256 + threadIdx.x;
  sd[threadIdx.x] = (i < N) ? deg[i] : 0;
  __syncthreads();
  for (int s = 128; s > 0; s >>= 1) {
    if (threadIdx.x < s) sd[threadIdx.x] += sd[threadIdx.x + s];
    __syncthreads();
  }
  if (threadIdx.x == 0) bsums[blockIdx.x] = sd[0];
}

// ---------------- scan step 2: final (bsums scanned redundantly per block) ----------------
__global__ void scan_final2(const int* __restrict__ deg, const int* __restrict__ bsums,
                            int* __restrict__ row_ptr, int* __restrict__ cursor,
                            int N, int NB) {
  __shared__ int sb[256];
  __shared__ int sd[256];
  int t = threadIdx.x;
  // inclusive scan of block sums (NB <= 256)
  int bv = (t < NB) ? bsums[t] : 0;
  sb[t] = bv;
  __syncthreads();
  for (int off = 1; off < 256; off <<= 1) {
    int add = (t >= off) ? sb[t - off] : 0;
    __syncthreads();
    sb[t] += add;
    __syncthreads();
  }
  int boff = (blockIdx.x == 0) ? 0 : sb[blockIdx.x - 1];
  // inclusive scan of this block's deg
  int i = blockIdx.x * 256 + t;
  int v = (i < N) ? deg[i] : 0;
  sd[t] = v;
  __syncthreads();
  for (int off = 1; off < 256; off <<= 1) {
    int add = (t >= off) ? sd[t - off] : 0;
    __syncthreads();
    sd[t] += add;
    __syncthreads();
  }
  int excl = sd[t] - v + boff;
  if (i < N) { row_ptr[i] = excl; cursor[i] = excl; }
  if (i == N - 1) row_ptr[N] = excl + v;
}

#define GLOAD_LDS16(g, l) \
  __builtin_amdgcn_global_load_lds((__attribute__((address_space(1))) const void*)(g), \
                                   (__attribute__((address_space(3))) void*)(l), 16, 0, 0)

// ---------------- fused: CSR scatter (blocks [0,sblocks)) + MFMA GEMM (rest) ----------------
// GEMM: Wh(bf16) = xb @ Wb^T, block covers BN=64 cols == one head; fused attention scores.
__global__ __launch_bounds__(256)
void scatter_gemm(const int* __restrict__ ei, int* __restrict__ cursor,
                  int* __restrict__ csr_src, int E, int sblocks,
                  const ushort_t* __restrict__ xb, const ushort_t* __restrict__ Wb,
                  ushort_t* __restrict__ Wh, float* __restrict__ s_src,
                  float* __restrict__ s_dst, const float* __restrict__ att,
                  int M, int gx) {
  __shared__ char lds[(BM + BN) * BK * 2];  // A: 16KB, B: 8KB
  const int bid = (int)blockIdx.x;
  if (bid < sblocks) {
    int t = bid * 256 + threadIdx.x;
    if (t < E) {
      int s = ei[t];
      int d = ei[E + t];
      int pos = atomicAdd(&cursor[d], 1);
      csr_src[pos] = s;
    }
    return;
  }
  const int gb = bid - sblocks;
  const int bx = gb % gx;
  const int by = gb / gx;
  const int tid = threadIdx.x;
  const int lane = tid & 63;
  const int w = tid >> 6;
  const int row0 = by * BM;
  const int col0 = bx * BN;
  char* As = lds;
  char* Bs = lds + BM * BK * 2;

  f32x4 acc[2][4] = {};

  for (int k0 = 0; k0 < KDIM; k0 += BK) {
#pragma unroll
    for (int i = 0; i < 4; ++i) {
      int c = i * 256 + tid;
      int row = c >> 3, c16 = c & 7;
      int q = c16 ^ (row & 7);
      const ushort_t* g = xb + (size_t)(row0 + row) * KDIM + k0 + q * 8;
      GLOAD_LDS16(g, As + (i * 256 + w * 64) * 16);
    }
#pragma unroll
    for (int i = 0; i < 2; ++i) {
      int c = i * 256 + tid;
      int row = c >> 3, c16 = c & 7;
      int q = c16 ^ (row & 7);
      const ushort_t* g = Wb + (size_t)(col0 + row) * KDIM + k0 + q * 8;
      GLOAD_LDS16(g, Bs + (i * 256 + w * 64) * 16);
    }
    __syncthreads();

#pragma unroll
    for (int kk = 0; kk < 2; ++kk) {
      bf16x8 aF[2], bF[4];
#pragma unroll
      for (int rt = 0; rt < 2; ++rt) {
        int r = w * 32 + rt * 16 + (lane & 15);
        int qq = kk * 4 + (lane >> 4);
        int phys = qq ^ (r & 7);
        aF[rt] = *(const bf16x8*)(As + r * 128 + phys * 16);
      }
#pragma unroll
      for (int ct = 0; ct < 4; ++ct) {
        int cl = ct * 16 + (lane & 15);
        int qq = kk * 4 + (lane >> 4);
        int phys = qq ^ (cl & 7);
        bF[ct] = *(const bf16x8*)(Bs + cl * 128 + phys * 16);
      }
#pragma unroll
      for (int rt = 0; rt < 2; ++rt)
#pragma unroll
        for (int ct = 0; ct < 4; ++ct)
          acc[rt][ct] = __builtin_amdgcn_mfma_f32_16x16x32_bf16(aF[rt], bF[ct], acc[rt][ct], 0, 0, 0);
    }
    __syncthreads();
  }

  // ---- fused per-node attention scores for head h = col0>>6 ----
  const int h = col0 >> 6;
  float att_s[4], att_d[4];
#pragma unroll
  for (int ct = 0; ct < 4; ++ct) {
    att_s[ct] = att[h * 2 * CC + ct * 16 + (lane & 15)];
    att_d[ct] = att[h * 2 * CC + CC + ct * 16 + (lane & 15)];
  }
#pragma unroll
  for (int rt = 0; rt < 2; ++rt) {
#pragma unroll
    for (int reg = 0; reg < 4; ++reg) {
      float ls = 0.f, ld_ = 0.f;
#pragma unroll
      for (int ct = 0; ct < 4; ++ct) {
        float a = acc[rt][ct][reg];
        ls += a * att_s[ct];
        ld_ += a * att_d[ct];
      }
#pragma unroll
      for (int off = 1; off < 16; off <<= 1) {
        ls += __shfl_xor(ls, off);
        ld_ += __shfl_xor(ld_, off);
      }
      int r = row0 + w * 32 + rt * 16 + (lane >> 4) * 4 + reg;
      if ((lane & 15) == 0 && r < M) {
        s_src[r * HH + h] = ls;
        s_dst[r * HH + h] = ld_;
      }
    }
  }

  // ---- Wh store (m89 layout: col=lane&15, row=(lane>>4)*4+reg) ----
#pragma unroll
  for (int rt = 0; rt < 2; ++rt) {
#pragma unroll
    for (int reg = 0; reg < 4; ++reg) {
      int r = row0 + w * 32 + rt * 16 + (lane >> 4) * 4 + reg;
      if (r < M) {
#pragma unroll
        for (int ct = 0; ct < 4; ++ct) {
          int ccol = col0 + ct * 16 + (lane & 15);
          Wh[(size_t)r * NOUT + ccol] = f2bf(acc[rt][ct][reg]);
        }
      }
    }
  }
}

// ---------------- aggregation: inline p=exp(leaky(.)), 4-deep MLP, fused ELU ----------------
__global__ __launch_bounds__(256)
void aggregate(const ushort_t* __restrict__ Wh, const float* __restrict__ s_src,
               const float* __restrict__ s_dst, const int* __restrict__ row_ptr,
               const int* __restrict__ csr_src, float* __restrict__ out, int N) {
  int wid = (int)((blockIdx.x * 256 + threadIdx.x) >> 6);
  int lane = threadIdx.x & 63;
  if (wid >= N) return;
  int half = lane >> 5, cl = lane & 31;
  int h = cl >> 3;
  int start = row_ptr[wid], end = row_ptr[wid + 1];
  float sd = s_dst[wid * HH + h];
  float acc[8] = {};
  float dsum = 0.f;
  int idx = start + half;
  // 4 edges in flight per half (8 per wave)
  for (; idx + 6 < end; idx += 8) {
    int s[4];
#pragma unroll
    for (int k = 0; k < 4; ++k) s[k] = csr_src[idx + 2 * k];
    float p[4];
    uint4 wv[4];
#pragma unroll
    for (int k = 0; k < 4; ++k) {
      float v = s_src[s[k] * HH + h] + sd;
      v = v > 0.f ? v : 0.2f * v;
      p[k] = __expf(v);
      wv[k] = *(const uint4*)(Wh + (size_t)s[k] * NOUT + cl * 8);
    }
#pragma unroll
    for (int k = 0; k < 4; ++k) {
      dsum += p[k];
#pragma unroll
      for (int j = 0; j < 4; ++j) {
        unsigned u = ((const unsigned*)&wv[k])[j];
        acc[2 * j]     += p[k] * __uint_as_float(u << 16);
        acc[2 * j + 1] += p[k] * __uint_as_float(u & 0xffff0000u);
      }
    }
  }
  for (; idx < end; idx += 2) {
    int s0 = csr_src[idx];
    float v = s_src[s0 * HH + h] + sd;
    v = v > 0.f ? v : 0.2f * v;
    float p0 = __expf(v);
    uint4 w0 = *(const uint4*)(Wh + (size_t)s0 * NOUT + cl * 8);
    dsum += p0;
#pragma unroll
    for (int j = 0; j < 4; ++j) {
      unsigned u0 = ((const unsigned*)&w0)[j];
      acc[2 * j]     += p0 * __uint_as_float(u0 << 16);
      acc[2 * j + 1] += p0 * __uint_as_float(u0 & 0xffff0000u);
    }
  }
#pragma unroll
  for (int j = 0; j < 8; ++j) acc[j] += __shfl_xor(acc[j], 32);
  dsum += __shfl_xor(dsum, 32);
  if (half == 0) {
    float rd = 1.0f / (dsum + 1e-16f);
    float o[8];
#pragma unroll
    for (int j = 0; j < 8; ++j) {
      float a = acc[j] * rd;
      o[j] = a > 0.f ? a : expm1f(a);
    }
    float* op = out + (size_t)wid * NOUT + cl * 8;
    *(float4*)op = make_float4(o[0], o[1], o[2], o[3]);
    *(float4*)(op + 4) = make_float4(o[4], o[5], o[6], o[7]);
  }
}

extern "C" void kernel_launch(void* const* d_in, const int* in_sizes, int n_in,
                              void* d_out, int out_size, void* d_ws, size_t ws_size,
                              hipStream_t stream) {
  const float* x = (const float*)d_in[0];
  const int* ei = (const int*)d_in[1];
  const float* W = (const float*)d_in[2];
  const float* att = (const float*)d_in[3];
  float* out = (float*)d_out;
  const int N = in_sizes[0] / KDIM;
  const int E = in_sizes[1] / 2;
  const int NPAD = ((N + BM - 1) / BM) * BM;
  const long long NK = (long long)N * KDIM;
  const long long NPK = (long long)NPAD * KDIM;
  const long long WK = (long long)NOUT * KDIM;

  char* p = (char*)d_ws;
  auto alloc = [&](size_t bytes) {
    char* r = p;
    p += (bytes + 255) & ~(size_t)255;
    return r;
  };
  ushort_t* xb   = (ushort_t*)alloc((size_t)NPK * 2);
  ushort_t* Wb   = (ushort_t*)alloc((size_t)WK * 2);
  ushort_t* Wh   = (ushort_t*)alloc((size_t)NPK * 2);
  float* s_src   = (float*)alloc((size_t)N * HH * 4);
  float* s_dst   = (float*)alloc((size_t)N * HH * 4);
  int* deg       = (int*)alloc((size_t)N * 4);
  int* row_ptr   = (int*)alloc((size_t)(N + 1) * 4);
  int* cursor    = (int*)alloc((size_t)N * 4);
  int* bsums     = (int*)alloc(256 * 4);
  int* csr_src   = (int*)alloc((size_t)E * 4);

  (void)hipMemsetAsync(deg, 0, (size_t)N * 4, stream);

  long long tot8 = (NPK + WK) / 8;
  int cblocks = (int)((tot8 + 255) / 256);
  int eblocks = (E + 255) / 256;
  convert_and_deg<<<cblocks + eblocks, 256, 0, stream>>>(x, W, xb, Wb, ei, deg,
                                                         NK, NPK, WK, cblocks, E);

  int NB = (N + 255) / 256;
  scan_partial<<<NB, 256, 0, stream>>>(deg, bsums, N);
  scan_final2<<<NB, 256, 0, stream>>>(deg, bsums, row_ptr, cursor, N, NB);

  int gx = NOUT / BN, gy = NPAD / BM;
  scatter_gemm<<<eblocks + gx * gy, 256, 0, stream>>>(ei, cursor, csr_src, E, eblocks,
                                                      xb, Wb, Wh, s_src, s_dst, att, N, gx);

  aggregate<<<(N + 3) / 4, 256, 0, stream>>>(Wh, s_src, s_dst, row_ptr, csr_src, out, N);
}

// Round 8
// 204.358 us; speedup vs baseline: 1.0893x; 1.0289x over previous
//
#include <hip/hip_runtime.h>
#include <hip/hip_bf16.h>
#include <cstdint>

#define HH 4
#define CC 64
#define KDIM 256   // IN_CH
#define NOUT 256   // H*C
#define BM 128
#define BN 64
#define BK 64

typedef __attribute__((ext_vector_type(8))) short bf16x8;
typedef __attribute__((ext_vector_type(4))) float f32x4;
typedef unsigned short ushort_t;

__device__ __forceinline__ unsigned short f2bf(float f) {
  unsigned u = __float_as_uint(f);
  unsigned r = (u + 0x7fff + ((u >> 16) & 1)) >> 16;  // RNE
  return (unsigned short)r;
}

// ---------------- fused: convert x,W to bf16 (+pad) AND degree count ----------------
__global__ __launch_bounds__(256)
void convert_and_deg(const float* __restrict__ x, const float* __restrict__ W,
                     ushort_t* __restrict__ xb, ushort_t* __restrict__ Wb,
                     const int* __restrict__ ei, int* __restrict__ deg,
                     long long NK, long long NPK, long long WK, int cblocks, int E) {
  if ((int)blockIdx.x < cblocks) {
    long long i = ((long long)blockIdx.x * 256 + threadIdx.x) * 8;
    if (i < NPK) {
      uint4 o = make_uint4(0u, 0u, 0u, 0u);
      if (i < NK) {
        float4 a = *(const float4*)(x + i);
        float4 b = *(const float4*)(x + i + 4);
        o.x = (unsigned)f2bf(a.x) | ((unsigned)f2bf(a.y) << 16);
        o.y = (unsigned)f2bf(a.z) | ((unsigned)f2bf(a.w) << 16);
        o.z = (unsigned)f2bf(b.x) | ((unsigned)f2bf(b.y) << 16);
        o.w = (unsigned)f2bf(b.z) | ((unsigned)f2bf(b.w) << 16);
      }
      *(uint4*)(xb + i) = o;
    } else {
      long long j = i - NPK;
      if (j < WK) {
        float4 a = *(const float4*)(W + j);
        float4 b = *(const float4*)(W + j + 4);
        uint4 o;
        o.x = (unsigned)f2bf(a.x) | ((unsigned)f2bf(a.y) << 16);
        o.y = (unsigned)f2bf(a.z) | ((unsigned)f2bf(a.w) << 16);
        o.z = (unsigned)f2bf(b.x) | ((unsigned)f2bf(b.y) << 16);
        o.w = (unsigned)f2bf(b.z) | ((unsigned)f2bf(b.w) << 16);
        *(uint4*)(Wb + j) = o;
      }
    }
  } else {
    int t = ((int)blockIdx.x - cblocks) * 256 + threadIdx.x;
    if (t < E) atomicAdd(&deg[ei[E + t]], 1);
  }
}

// ---------------- scan step 1: per-block sums ----------------
__global__ void scan_partial(const int* __restrict__ deg, int* __restrict__ bsums, int N) {
  __shared__ int sd[256];
  int i = blockIdx.x * 256 + threadIdx.x;
  sd[threadIdx.x] = (i < N) ? deg[i] : 0;
  __syncthreads();
  for (int s = 128; s > 0; s >>= 1) {
    if (threadIdx.x < s) sd[threadIdx.x] += sd[threadIdx.x + s];
    __syncthreads();
  }
  if (threadIdx.x == 0) bsums[blockIdx.x] = sd[0];
}

// ---------------- scan step 2: final (bsums scanned redundantly per block) ----------------
__global__ void scan_final2(const int* __restrict__ deg, const int* __restrict__ bsums,
                            int* __restrict__ row_ptr, int* __restrict__ cursor,
                            int N, int NB) {
  __shared__ int sb[256];
  __shared__ int sd[256];
  int t = threadIdx.x;
  int bv = (t < NB) ? bsums[t] : 0;
  sb[t] = bv;
  __syncthreads();
  for (int off = 1; off < 256; off <<= 1) {
    int add = (t >= off) ? sb[t - off] : 0;
    __syncthreads();
    sb[t] += add;
    __syncthreads();
  }
  int boff = (blockIdx.x == 0) ? 0 : sb[blockIdx.x - 1];
  int i = blockIdx.x * 256 + t;
  int v = (i < N) ? deg[i] : 0;
  sd[t] = v;
  __syncthreads();
  for (int off = 1; off < 256; off <<= 1) {
    int add = (t >= off) ? sd[t - off] : 0;
    __syncthreads();
    sd[t] += add;
    __syncthreads();
  }
  int excl = sd[t] - v + boff;
  if (i < N) { row_ptr[i] = excl; cursor[i] = excl; }
  if (i == N - 1) row_ptr[N] = excl + v;
}

// ---------------- CSR scatter (indices only) ----------------
__global__ __launch_bounds__(256)
void csr_scatter(const int* __restrict__ ei, int* __restrict__ cursor,
                 int* __restrict__ csr_src, int E) {
  int t = blockIdx.x * 256 + threadIdx.x;
  if (t >= E) return;
  int s = ei[t];
  int d = ei[E + t];
  int pos = atomicAdd(&cursor[d], 1);
  csr_src[pos] = s;
}

#define GLOAD_LDS16(g, l) \
  __builtin_amdgcn_global_load_lds((__attribute__((address_space(1))) const void*)(g), \
                                   (__attribute__((address_space(3))) void*)(l), 16, 0, 0)

// ---------------- MFMA GEMM, double-buffered pipeline: Wh(bf16) = xb @ Wb^T ----------------
// Block covers BN=64 cols == exactly one head h = col0>>6. Fused attention scores.
__global__ __launch_bounds__(256)
void gemm_bf16(const ushort_t* __restrict__ xb, const ushort_t* __restrict__ Wb,
               ushort_t* __restrict__ Wh, float* __restrict__ s_src,
               float* __restrict__ s_dst, const float* __restrict__ att, int M) {
  __shared__ char lds[2][(BM + BN) * BK * 2];  // 2 x (A 16KB + B 8KB)
  const int tid = threadIdx.x;
  const int lane = tid & 63;
  const int w = tid >> 6;
  const int row0 = blockIdx.y * BM;
  const int col0 = blockIdx.x * BN;

  // staging chunk coords (chunk c -> LDS linear c*16, global row=c>>3, group (c&7)^(row&7))
  int arow[4], aq[4], brow[2], bq[2];
#pragma unroll
  for (int i = 0; i < 4; ++i) {
    int c = i * 256 + tid;
    arow[i] = c >> 3;
    aq[i] = (c & 7) ^ (arow[i] & 7);
  }
#pragma unroll
  for (int i = 0; i < 2; ++i) {
    int c = i * 256 + tid;
    brow[i] = c >> 3;
    bq[i] = (c & 7) ^ (brow[i] & 7);
  }

  f32x4 acc[2][4] = {};

#define STAGE(buf, k0_)                                                              \
  {                                                                                  \
    char* As_ = lds[buf];                                                            \
    char* Bs_ = lds[buf] + BM * BK * 2;                                              \
    _Pragma("unroll")                                                                \
    for (int i = 0; i < 4; ++i) {                                                    \
      const ushort_t* g = xb + (size_t)(row0 + arow[i]) * KDIM + (k0_) + aq[i] * 8;  \
      GLOAD_LDS16(g, As_ + (i * 256 + w * 64) * 16);                                 \
    }                                                                                \
    _Pragma("unroll")                                                                \
    for (int i = 0; i < 2; ++i) {                                                    \
      const ushort_t* g = Wb + (size_t)(col0 + brow[i]) * KDIM + (k0_) + bq[i] * 8;  \
      GLOAD_LDS16(g, Bs_ + (i * 256 + w * 64) * 16);                                 \
    }                                                                                \
  }

#define COMPUTE(buf)                                                                 \
  {                                                                                  \
    char* As_ = lds[buf];                                                            \
    char* Bs_ = lds[buf] + BM * BK * 2;                                              \
    _Pragma("unroll")                                                                \
    for (int kk = 0; kk < 2; ++kk) {                                                 \
      bf16x8 aF[2], bF[4];                                                           \
      _Pragma("unroll")                                                              \
      for (int rt = 0; rt < 2; ++rt) {                                               \
        int r = w * 32 + rt * 16 + (lane & 15);                                      \
        int qq = kk * 4 + (lane >> 4);                                               \
        int phys = qq ^ (r & 7);                                                     \
        aF[rt] = *(const bf16x8*)(As_ + r * 128 + phys * 16);                        \
      }                                                                              \
      _Pragma("unroll")                                                              \
      for (int ct = 0; ct < 4; ++ct) {                                               \
        int cl = ct * 16 + (lane & 15);                                              \
        int qq = kk * 4 + (lane >> 4);                                               \
        int phys = qq ^ (cl & 7);                                                    \
        bF[ct] = *(const bf16x8*)(Bs_ + cl * 128 + phys * 16);                       \
      }                                                                              \
      _Pragma("unroll")                                                              \
      for (int rt = 0; rt < 2; ++rt)                                                 \
        _Pragma("unroll")                                                            \
        for (int ct = 0; ct < 4; ++ct)                                               \
          acc[rt][ct] = __builtin_amdgcn_mfma_f32_16x16x32_bf16(aF[rt], bF[ct],      \
                                                                acc[rt][ct], 0, 0, 0);\
    }                                                                                \
  }

  // prologue
  STAGE(0, 0);
  __syncthreads();                 // drains vmcnt(0)
  // pipelined K-steps: stage(t+1) issued before compute(t); barrier drain overlaps compute
#pragma unroll
  for (int t = 0; t < 3; ++t) {
    STAGE((t + 1) & 1, (t + 1) * BK);
    COMPUTE(t & 1);
    __syncthreads();               // waits vmcnt(0): stage(t+1) done; lds[t&1] free
  }
  COMPUTE(1);                      // t=3, buffer 1

  // ---- fused per-node attention scores for head h = col0>>6 ----
  const int h = col0 >> 6;
  float att_s[4], att_d[4];
#pragma unroll
  for (int ct = 0; ct < 4; ++ct) {
    att_s[ct] = att[h * 2 * CC + ct * 16 + (lane & 15)];
    att_d[ct] = att[h * 2 * CC + CC + ct * 16 + (lane & 15)];
  }
#pragma unroll
  for (int rt = 0; rt < 2; ++rt) {
#pragma unroll
    for (int reg = 0; reg < 4; ++reg) {
      float ls = 0.f, ld_ = 0.f;
#pragma unroll
      for (int ct = 0; ct < 4; ++ct) {
        float a = acc[rt][ct][reg];
        ls += a * att_s[ct];
        ld_ += a * att_d[ct];
      }
#pragma unroll
      for (int off = 1; off < 16; off <<= 1) {
        ls += __shfl_xor(ls, off);
        ld_ += __shfl_xor(ld_, off);
      }
      int r = row0 + w * 32 + rt * 16 + (lane >> 4) * 4 + reg;
      if ((lane & 15) == 0 && r < M) {
        s_src[r * HH + h] = ls;
        s_dst[r * HH + h] = ld_;
      }
    }
  }

  // ---- Wh store (m89 layout: col=lane&15, row=(lane>>4)*4+reg) ----
#pragma unroll
  for (int rt = 0; rt < 2; ++rt) {
#pragma unroll
    for (int reg = 0; reg < 4; ++reg) {
      int r = row0 + w * 32 + rt * 16 + (lane >> 4) * 4 + reg;
      if (r < M) {
#pragma unroll
        for (int ct = 0; ct < 4; ++ct) {
          int ccol = col0 + ct * 16 + (lane & 15);
          Wh[(size_t)r * NOUT + ccol] = f2bf(acc[rt][ct][reg]);
        }
      }
    }
  }
}

// ---------------- aggregation: inline p=exp(leaky(.)), 4-deep MLP, fused ELU ----------------
__global__ __launch_bounds__(256)
void aggregate(const ushort_t* __restrict__ Wh, const float* __restrict__ s_src,
               const float* __restrict__ s_dst, const int* __restrict__ row_ptr,
               const int* __restrict__ csr_src, float* __restrict__ out, int N) {
  int wid = (int)((blockIdx.x * 256 + threadIdx.x) >> 6);
  int lane = threadIdx.x & 63;
  if (wid >= N) return;
  int half = lane >> 5, cl = lane & 31;
  int h = cl >> 3;
  int start = row_ptr[wid], end = row_ptr[wid + 1];
  float sd = s_dst[wid * HH + h];
  float acc[8] = {};
  float dsum = 0.f;
  int idx = start + half;
  for (; idx + 6 < end; idx += 8) {
    int s[4];
#pragma unroll
    for (int k = 0; k < 4; ++k) s[k] = csr_src[idx + 2 * k];
    float p[4];
    uint4 wv[4];
#pragma unroll
    for (int k = 0; k < 4; ++k) {
      float v = s_src[s[k] * HH + h] + sd;
      v = v > 0.f ? v : 0.2f * v;
      p[k] = __expf(v);
      wv[k] = *(const uint4*)(Wh + (size_t)s[k] * NOUT + cl * 8);
    }
#pragma unroll
    for (int k = 0; k < 4; ++k) {
      dsum += p[k];
#pragma unroll
      for (int j = 0; j < 4; ++j) {
        unsigned u = ((const unsigned*)&wv[k])[j];
        acc[2 * j]     += p[k] * __uint_as_float(u << 16);
        acc[2 * j + 1] += p[k] * __uint_as_float(u & 0xffff0000u);
      }
    }
  }
  for (; idx < end; idx += 2) {
    int s0 = csr_src[idx];
    float v = s_src[s0 * HH + h] + sd;
    v = v > 0.f ? v : 0.2f * v;
    float p0 = __expf(v);
    uint4 w0 = *(const uint4*)(Wh + (size_t)s0 * NOUT + cl * 8);
    dsum += p0;
#pragma unroll
    for (int j = 0; j < 4; ++j) {
      unsigned u0 = ((const unsigned*)&w0)[j];
      acc[2 * j]     += p0 * __uint_as_float(u0 << 16);
      acc[2 * j + 1] += p0 * __uint_as_float(u0 & 0xffff0000u);
    }
  }
#pragma unroll
  for (int j = 0; j < 8; ++j) acc[j] += __shfl_xor(acc[j], 32);
  dsum += __shfl_xor(dsum, 32);
  if (half == 0) {
    float rd = 1.0f / (dsum + 1e-16f);
    float o[8];
#pragma unroll
    for (int j = 0; j < 8; ++j) {
      float a = acc[j] * rd;
      o[j] = a > 0.f ? a : expm1f(a);
    }
    float* op = out + (size_t)wid * NOUT + cl * 8;
    *(float4*)op = make_float4(o[0], o[1], o[2], o[3]);
    *(float4*)(op + 4) = make_float4(o[4], o[5], o[6], o[7]);
  }
}

extern "C" void kernel_launch(void* const* d_in, const int* in_sizes, int n_in,
                              void* d_out, int out_size, void* d_ws, size_t ws_size,
                              hipStream_t stream) {
  const float* x = (const float*)d_in[0];
  const int* ei = (const int*)d_in[1];
  const float* W = (const float*)d_in[2];
  const float* att = (const float*)d_in[3];
  float* out = (float*)d_out;
  const int N = in_sizes[0] / KDIM;
  const int E = in_sizes[1] / 2;
  const int NPAD = ((N + BM - 1) / BM) * BM;
  const long long NK = (long long)N * KDIM;
  const long long NPK = (long long)NPAD * KDIM;
  const long long WK = (long long)NOUT * KDIM;

  char* p = (char*)d_ws;
  auto alloc = [&](size_t bytes) {
    char* r = p;
    p += (bytes + 255) & ~(size_t)255;
    return r;
  };
  ushort_t* xb   = (ushort_t*)alloc((size_t)NPK * 2);
  ushort_t* Wb   = (ushort_t*)alloc((size_t)WK * 2);
  ushort_t* Wh   = (ushort_t*)alloc((size_t)NPK * 2);
  float* s_src   = (float*)alloc((size_t)N * HH * 4);
  float* s_dst   = (float*)alloc((size_t)N * HH * 4);
  int* deg       = (int*)alloc((size_t)N * 4);
  int* row_ptr   = (int*)alloc((size_t)(N + 1) * 4);
  int* cursor    = (int*)alloc((size_t)N * 4);
  int* bsums     = (int*)alloc(256 * 4);
  int* csr_src   = (int*)alloc((size_t)E * 4);

  (void)hipMemsetAsync(deg, 0, (size_t)N * 4, stream);

  long long tot8 = (NPK + WK) / 8;
  int cblocks = (int)((tot8 + 255) / 256);
  int eblocks = (E + 255) / 256;
  convert_and_deg<<<cblocks + eblocks, 256, 0, stream>>>(x, W, xb, Wb, ei, deg,
                                                         NK, NPK, WK, cblocks, E);

  int NB = (N + 255) / 256;
  scan_partial<<<NB, 256, 0, stream>>>(deg, bsums, N);
  scan_final2<<<NB, 256, 0, stream>>>(deg, bsums, row_ptr, cursor, N, NB);

  csr_scatter<<<eblocks, 256, 0, stream>>>(ei, cursor, csr_src, E);

  dim3 gg(NOUT / BN, NPAD / BM);
  gemm_bf16<<<gg, 256, 0, stream>>>(xb, Wb, Wh, s_src, s_dst, att, N);

  aggregate<<<(N + 3) / 4, 256, 0, stream>>>(Wh, s_src, s_dst, row_ptr, csr_src, out, N);
}

// Round 9
// 204.351 us; speedup vs baseline: 1.0894x; 1.0000x over previous
//
#include <hip/hip_runtime.h>
#include <hip/hip_bf16.h>
#include <cstdint>

#define HH 4
#define CC 64
#define KDIM 256   // IN_CH
#define NOUT 256   // H*C
#define BM 128
#define BN 64
#define BK 64

typedef __attribute__((ext_vector_type(8))) short bf16x8;
typedef __attribute__((ext_vector_type(4))) float f32x4;
typedef unsigned short ushort_t;

__device__ __forceinline__ unsigned short f2bf(float f) {
  unsigned u = __float_as_uint(f);
  unsigned r = (u + 0x7fff + ((u >> 16) & 1)) >> 16;  // RNE
  return (unsigned short)r;
}

// ---------------- fused: convert x,W to bf16 (+pad) AND degree count ----------------
__global__ __launch_bounds__(256)
void convert_and_deg(const float* __restrict__ x, const float* __restrict__ W,
                     ushort_t* __restrict__ xb, ushort_t* __restrict__ Wb,
                     const int* __restrict__ ei, int* __restrict__ deg,
                     long long NK, long long NPK, long long WK, int cblocks, int E) {
  if ((int)blockIdx.x < cblocks) {
    long long i = ((long long)blockIdx.x * 256 + threadIdx.x) * 8;
    if (i < NPK) {
      uint4 o = make_uint4(0u, 0u, 0u, 0u);
      if (i < NK) {
        float4 a = *(const float4*)(x + i);
        float4 b = *(const float4*)(x + i + 4);
        o.x = (unsigned)f2bf(a.x) | ((unsigned)f2bf(a.y) << 16);
        o.y = (unsigned)f2bf(a.z) | ((unsigned)f2bf(a.w) << 16);
        o.z = (unsigned)f2bf(b.x) | ((unsigned)f2bf(b.y) << 16);
        o.w = (unsigned)f2bf(b.z) | ((unsigned)f2bf(b.w) << 16);
      }
      *(uint4*)(xb + i) = o;
    } else {
      long long j = i - NPK;
      if (j < WK) {
        float4 a = *(const float4*)(W + j);
        float4 b = *(const float4*)(W + j + 4);
        uint4 o;
        o.x = (unsigned)f2bf(a.x) | ((unsigned)f2bf(a.y) << 16);
        o.y = (unsigned)f2bf(a.z) | ((unsigned)f2bf(a.w) << 16);
        o.z = (unsigned)f2bf(b.x) | ((unsigned)f2bf(b.y) << 16);
        o.w = (unsigned)f2bf(b.z) | ((unsigned)f2bf(b.w) << 16);
        *(uint4*)(Wb + j) = o;
      }
    }
  } else {
    int t = ((int)blockIdx.x - cblocks) * 256 + threadIdx.x;
    if (t < E) atomicAdd(&deg[ei[E + t]], 1);
  }
}

// ---------------- single-dispatch exclusive scan: decoupled lookback ----------------
// bstate[b] = (flag<<32)|sum, flag 1=aggregate ready, 2=inclusive-prefix ready.
// Arrival-order tickets make the lookback deadlock-free (a ticket only waits on
// earlier tickets, which are held by blocks that have already started).
__global__ __launch_bounds__(256)
void scan_lookback(const int* __restrict__ deg, int* __restrict__ row_ptr,
                   int* __restrict__ cursor, int* __restrict__ ticket,
                   unsigned long long* __restrict__ bstate, int N) {
  __shared__ int sd[256];
  __shared__ int s_b;
  __shared__ int s_prev;
  int t = threadIdx.x;
  if (t == 0) s_b = atomicAdd(ticket, 1);
  __syncthreads();
  int b = s_b;
  int i = b * 256 + t;
  int v = (i < N) ? deg[i] : 0;
  sd[t] = v;
  __syncthreads();
  for (int off = 1; off < 256; off <<= 1) {
    int add = (t >= off) ? sd[t - off] : 0;
    __syncthreads();
    sd[t] += add;
    __syncthreads();
  }
  int total = sd[255];
  if (t == 0) {
    if (b == 0) {
      atomicExch(&bstate[0], (2ULL << 32) | (unsigned)total);
      s_prev = 0;
    } else {
      atomicExch(&bstate[b], (1ULL << 32) | (unsigned)total);
      unsigned long long run = 0;
      int j = b - 1;
      while (j >= 0) {
        unsigned long long st;
        do { st = atomicAdd(&bstate[j], 0ULL); } while ((st >> 32) == 0ULL);
        run += (unsigned)st;
        if ((st >> 32) == 2ULL) break;
        --j;
      }
      s_prev = (int)run;
      atomicExch(&bstate[b], (2ULL << 32) | (unsigned)(run + (unsigned)total));
    }
  }
  __syncthreads();
  int excl = sd[t] - v + s_prev;
  if (i < N) { row_ptr[i] = excl; cursor[i] = excl; }
  if (i == N - 1) row_ptr[N] = excl + v;
}

// ---------------- CSR scatter (indices only) ----------------
__global__ __launch_bounds__(256)
void csr_scatter(const int* __restrict__ ei, int* __restrict__ cursor,
                 int* __restrict__ csr_src, int E) {
  int t = blockIdx.x * 256 + threadIdx.x;
  if (t >= E) return;
  int s = ei[t];
  int d = ei[E + t];
  int pos = atomicAdd(&cursor[d], 1);
  csr_src[pos] = s;
}

#define GLOAD_LDS16(g, l) \
  __builtin_amdgcn_global_load_lds((__attribute__((address_space(1))) const void*)(g), \
                                   (__attribute__((address_space(3))) void*)(l), 16, 0, 0)

// ---------------- MFMA GEMM (single-buffer): Wh(bf16) = xb @ Wb^T + fused scores ----------------
// Block covers BN=64 cols == exactly one head h = col0>>6.
__global__ __launch_bounds__(256)
void gemm_bf16(const ushort_t* __restrict__ xb, const ushort_t* __restrict__ Wb,
               ushort_t* __restrict__ Wh, float* __restrict__ s_src,
               float* __restrict__ s_dst, const float* __restrict__ att, int M) {
  __shared__ char lds[(BM + BN) * BK * 2];  // A: 16KB, B: 8KB
  const int tid = threadIdx.x;
  const int lane = tid & 63;
  const int w = tid >> 6;
  const int row0 = blockIdx.y * BM;
  const int col0 = blockIdx.x * BN;
  char* As = lds;
  char* Bs = lds + BM * BK * 2;

  f32x4 acc[2][4] = {};

  for (int k0 = 0; k0 < KDIM; k0 += BK) {
#pragma unroll
    for (int i = 0; i < 4; ++i) {
      int c = i * 256 + tid;
      int row = c >> 3, c16 = c & 7;
      int q = c16 ^ (row & 7);
      const ushort_t* g = xb + (size_t)(row0 + row) * KDIM + k0 + q * 8;
      GLOAD_LDS16(g, As + (i * 256 + w * 64) * 16);
    }
#pragma unroll
    for (int i = 0; i < 2; ++i) {
      int c = i * 256 + tid;
      int row = c >> 3, c16 = c & 7;
      int q = c16 ^ (row & 7);
      const ushort_t* g = Wb + (size_t)(col0 + row) * KDIM + k0 + q * 8;
      GLOAD_LDS16(g, Bs + (i * 256 + w * 64) * 16);
    }
    __syncthreads();

#pragma unroll
    for (int kk = 0; kk < 2; ++kk) {
      bf16x8 aF[2], bF[4];
#pragma unroll
      for (int rt = 0; rt < 2; ++rt) {
        int r = w * 32 + rt * 16 + (lane & 15);
        int qq = kk * 4 + (lane >> 4);
        int phys = qq ^ (r & 7);
        aF[rt] = *(const bf16x8*)(As + r * 128 + phys * 16);
      }
#pragma unroll
      for (int ct = 0; ct < 4; ++ct) {
        int cl = ct * 16 + (lane & 15);
        int qq = kk * 4 + (lane >> 4);
        int phys = qq ^ (cl & 7);
        bF[ct] = *(const bf16x8*)(Bs + cl * 128 + phys * 16);
      }
#pragma unroll
      for (int rt = 0; rt < 2; ++rt)
#pragma unroll
        for (int ct = 0; ct < 4; ++ct)
          acc[rt][ct] = __builtin_amdgcn_mfma_f32_16x16x32_bf16(aF[rt], bF[ct], acc[rt][ct], 0, 0, 0);
    }
    __syncthreads();
  }

  // ---- fused per-node attention scores for head h = col0>>6 ----
  const int h = col0 >> 6;
  float att_s[4], att_d[4];
#pragma unroll
  for (int ct = 0; ct < 4; ++ct) {
    att_s[ct] = att[h * 2 * CC + ct * 16 + (lane & 15)];
    att_d[ct] = att[h * 2 * CC + CC + ct * 16 + (lane & 15)];
  }
#pragma unroll
  for (int rt = 0; rt < 2; ++rt) {
#pragma unroll
    for (int reg = 0; reg < 4; ++reg) {
      float ls = 0.f, ld_ = 0.f;
#pragma unroll
      for (int ct = 0; ct < 4; ++ct) {
        float a = acc[rt][ct][reg];
        ls += a * att_s[ct];
        ld_ += a * att_d[ct];
      }
#pragma unroll
      for (int off = 1; off < 16; off <<= 1) {
        ls += __shfl_xor(ls, off);
        ld_ += __shfl_xor(ld_, off);
      }
      int r = row0 + w * 32 + rt * 16 + (lane >> 4) * 4 + reg;
      if ((lane & 15) == 0 && r < M) {
        s_src[r * HH + h] = ls;
        s_dst[r * HH + h] = ld_;
      }
    }
  }

  // ---- Wh store (m89 layout: col=lane&15, row=(lane>>4)*4+reg) ----
#pragma unroll
  for (int rt = 0; rt < 2; ++rt) {
#pragma unroll
    for (int reg = 0; reg < 4; ++reg) {
      int r = row0 + w * 32 + rt * 16 + (lane >> 4) * 4 + reg;
      if (r < M) {
#pragma unroll
        for (int ct = 0; ct < 4; ++ct) {
          int ccol = col0 + ct * 16 + (lane & 15);
          Wh[(size_t)r * NOUT + ccol] = f2bf(acc[rt][ct][reg]);
        }
      }
    }
  }
}

// ---------------- aggregation: inline p=exp(leaky(.)), 4-deep MLP, fused ELU ----------------
__global__ __launch_bounds__(256)
void aggregate(const ushort_t* __restrict__ Wh, const float* __restrict__ s_src,
               const float* __restrict__ s_dst, const int* __restrict__ row_ptr,
               const int* __restrict__ csr_src, float* __restrict__ out, int N) {
  int wid = (int)((blockIdx.x * 256 + threadIdx.x) >> 6);
  int lane = threadIdx.x & 63;
  if (wid >= N) return;
  int half = lane >> 5, cl = lane & 31;
  int h = cl >> 3;
  int start = row_ptr[wid], end = row_ptr[wid + 1];
  float sd = s_dst[wid * HH + h];
  float acc[8] = {};
  float dsum = 0.f;
  int idx = start + half;
  for (; idx + 6 < end; idx += 8) {
    int s[4];
#pragma unroll
    for (int k = 0; k < 4; ++k) s[k] = csr_src[idx + 2 * k];
    float p[4];
    uint4 wv[4];
#pragma unroll
    for (int k = 0; k < 4; ++k) {
      float v = s_src[s[k] * HH + h] + sd;
      v = v > 0.f ? v : 0.2f * v;
      p[k] = __expf(v);
      wv[k] = *(const uint4*)(Wh + (size_t)s[k] * NOUT + cl * 8);
    }
#pragma unroll
    for (int k = 0; k < 4; ++k) {
      dsum += p[k];
#pragma unroll
      for (int j = 0; j < 4; ++j) {
        unsigned u = ((const unsigned*)&wv[k])[j];
        acc[2 * j]     += p[k] * __uint_as_float(u << 16);
        acc[2 * j + 1] += p[k] * __uint_as_float(u & 0xffff0000u);
      }
    }
  }
  for (; idx < end; idx += 2) {
    int s0 = csr_src[idx];
    float v = s_src[s0 * HH + h] + sd;
    v = v > 0.f ? v : 0.2f * v;
    float p0 = __expf(v);
    uint4 w0 = *(const uint4*)(Wh + (size_t)s0 * NOUT + cl * 8);
    dsum += p0;
#pragma unroll
    for (int j = 0; j < 4; ++j) {
      unsigned u0 = ((const unsigned*)&w0)[j];
      acc[2 * j]     += p0 * __uint_as_float(u0 << 16);
      acc[2 * j + 1] += p0 * __uint_as_float(u0 & 0xffff0000u);
    }
  }
#pragma unroll
  for (int j = 0; j < 8; ++j) acc[j] += __shfl_xor(acc[j], 32);
  dsum += __shfl_xor(dsum, 32);
  if (half == 0) {
    float rd = 1.0f / (dsum + 1e-16f);
    float o[8];
#pragma unroll
    for (int j = 0; j < 8; ++j) {
      float a = acc[j] * rd;
      o[j] = a > 0.f ? a : expm1f(a);
    }
    float* op = out + (size_t)wid * NOUT + cl * 8;
    *(float4*)op = make_float4(o[0], o[1], o[2], o[3]);
    *(float4*)(op + 4) = make_float4(o[4], o[5], o[6], o[7]);
  }
}

extern "C" void kernel_launch(void* const* d_in, const int* in_sizes, int n_in,
                              void* d_out, int out_size, void* d_ws, size_t ws_size,
                              hipStream_t stream) {
  const float* x = (const float*)d_in[0];
  const int* ei = (const int*)d_in[1];
  const float* W = (const float*)d_in[2];
  const float* att = (const float*)d_in[3];
  float* out = (float*)d_out;
  const int N = in_sizes[0] / KDIM;
  const int E = in_sizes[1] / 2;
  const int NPAD = ((N + BM - 1) / BM) * BM;
  const long long NK = (long long)N * KDIM;
  const long long NPK = (long long)NPAD * KDIM;
  const long long WK = (long long)NOUT * KDIM;
  const int NB = (N + 255) / 256;

  char* p = (char*)d_ws;
  auto alloc = [&](size_t bytes) {
    char* r = p;
    p += (bytes + 255) & ~(size_t)255;
    return r;
  };
  ushort_t* xb   = (ushort_t*)alloc((size_t)NPK * 2);
  ushort_t* Wb   = (ushort_t*)alloc((size_t)WK * 2);
  ushort_t* Wh   = (ushort_t*)alloc((size_t)NPK * 2);
  float* s_src   = (float*)alloc((size_t)N * HH * 4);
  float* s_dst   = (float*)alloc((size_t)N * HH * 4);
  char* zbase    = p;
  int* deg       = (int*)alloc((size_t)N * 4);
  int* ticket    = (int*)alloc(256);
  unsigned long long* bstate = (unsigned long long*)alloc((size_t)NB * 8);
  size_t zbytes  = (size_t)(p - zbase);
  int* row_ptr   = (int*)alloc((size_t)(N + 1) * 4);
  int* cursor    = (int*)alloc((size_t)N * 4);
  int* csr_src   = (int*)alloc((size_t)E * 4);

  (void)hipMemsetAsync(zbase, 0, zbytes, stream);

  long long tot8 = (NPK + WK) / 8;
  int cblocks = (int)((tot8 + 255) / 256);
  int eblocks = (E + 255) / 256;
  convert_and_deg<<<cblocks + eblocks, 256, 0, stream>>>(x, W, xb, Wb, ei, deg,
                                                         NK, NPK, WK, cblocks, E);

  scan_lookback<<<NB, 256, 0, stream>>>(deg, row_ptr, cursor, ticket, bstate, N);

  csr_scatter<<<eblocks, 256, 0, stream>>>(ei, cursor, csr_src, E);

  dim3 gg(NOUT / BN, NPAD / BM);
  gemm_bf16<<<gg, 256, 0, stream>>>(xb, Wb, Wh, s_src, s_dst, att, N);

  aggregate<<<(N + 3) / 4, 256, 0, stream>>>(Wh, s_src, s_dst, row_ptr, csr_src, out, N);
}

// Round 10
// 194.076 us; speedup vs baseline: 1.1470x; 1.0529x over previous
//
#include <hip/hip_runtime.h>
#include <hip/hip_bf16.h>
#include <cstdint>

#define HH 4
#define CC 64
#define KDIM 256   // IN_CH
#define NOUT 256   // H*C
#define BM 64
#define BK 64

typedef __attribute__((ext_vector_type(8))) short bf16x8;
typedef __attribute__((ext_vector_type(4))) float f32x4;
typedef unsigned short ushort_t;

__device__ __forceinline__ unsigned short f2bf(float f) {
  unsigned u = __float_as_uint(f);
  unsigned r = (u + 0x7fff + ((u >> 16) & 1)) >> 16;  // RNE
  return (unsigned short)r;
}
__device__ __forceinline__ unsigned pk2bf(float lo, float hi) {
  return (unsigned)f2bf(lo) | ((unsigned)f2bf(hi) << 16);
}

// ---------------- fused: convert W to bf16 (32 blocks) + degree count ----------------
__global__ __launch_bounds__(256)
void deg_convW(const float* __restrict__ W, ushort_t* __restrict__ Wb,
               const int* __restrict__ ei, int* __restrict__ deg,
               int wblocks, int E) {
  if ((int)blockIdx.x < wblocks) {
    int i = ((int)blockIdx.x * 256 + threadIdx.x) * 8;   // < 65536
    float4 a = *(const float4*)(W + i);
    float4 b = *(const float4*)(W + i + 4);
    uint4 o;
    o.x = pk2bf(a.x, a.y);
    o.y = pk2bf(a.z, a.w);
    o.z = pk2bf(b.x, b.y);
    o.w = pk2bf(b.z, b.w);
    *(uint4*)(Wb + i) = o;
  } else {
    int t = ((int)blockIdx.x - wblocks) * 256 + threadIdx.x;
    if (t < E) atomicAdd(&deg[ei[E + t]], 1);
  }
}

// ---------------- scan step 1: per-block sums ----------------
__global__ void scan_partial(const int* __restrict__ deg, int* __restrict__ bsums, int N) {
  __shared__ int sd[256];
  int i = blockIdx.x * 256 + threadIdx.x;
  sd[threadIdx.x] = (i < N) ? deg[i] : 0;
  __syncthreads();
  for (int s = 128; s > 0; s >>= 1) {
    if (threadIdx.x < s) sd[threadIdx.x] += sd[threadIdx.x + s];
    __syncthreads();
  }
  if (threadIdx.x == 0) bsums[blockIdx.x] = sd[0];
}

// ---------------- scan step 2: final (bsums scanned redundantly per block) ----------------
__global__ void scan_final2(const int* __restrict__ deg, const int* __restrict__ bsums,
                            int* __restrict__ row_ptr, int* __restrict__ cursor,
                            int N, int NB) {
  __shared__ int sb[256];
  __shared__ int sd[256];
  int t = threadIdx.x;
  int bv = (t < NB) ? bsums[t] : 0;
  sb[t] = bv;
  __syncthreads();
  for (int off = 1; off < 256; off <<= 1) {
    int add = (t >= off) ? sb[t - off] : 0;
    __syncthreads();
    sb[t] += add;
    __syncthreads();
  }
  int boff = (blockIdx.x == 0) ? 0 : sb[blockIdx.x - 1];
  int i = blockIdx.x * 256 + t;
  int v = (i < N) ? deg[i] : 0;
  sd[t] = v;
  __syncthreads();
  for (int off = 1; off < 256; off <<= 1) {
    int add = (t >= off) ? sd[t - off] : 0;
    __syncthreads();
    sd[t] += add;
    __syncthreads();
  }
  int excl = sd[t] - v + boff;
  if (i < N) { row_ptr[i] = excl; cursor[i] = excl; }
  if (i == N - 1) row_ptr[N] = excl + v;
}

// ---------------- CSR scatter (indices only) ----------------
__global__ __launch_bounds__(256)
void csr_scatter(const int* __restrict__ ei, int* __restrict__ cursor,
                 int* __restrict__ csr_src, int E) {
  int t = blockIdx.x * 256 + threadIdx.x;
  if (t >= E) return;
  int s = ei[t];
  int d = ei[E + t];
  int pos = atomicAdd(&cursor[d], 1);
  csr_src[pos] = s;
}

#define GLOAD_LDS16(g, l) \
  __builtin_amdgcn_global_load_lds((__attribute__((address_space(1))) const void*)(g), \
                                   (__attribute__((address_space(3))) void*)(l), 16, 0, 0)

// ---------------- MFMA GEMM 64x256: Wh(bf16) = x(fp32) @ Wb^T + fused scores ----------------
// One block = 64 rows x all 256 cols; wave w owns head w (cols w*64..w*64+63).
// x is read exactly ONCE (no column-block re-reads) -> fp32-direct staging is cheap.
__global__ __launch_bounds__(256)
void gemm_direct(const float* __restrict__ X, const ushort_t* __restrict__ Wb,
                 ushort_t* __restrict__ Wh, float* __restrict__ s_src,
                 float* __restrict__ s_dst, const float* __restrict__ att, int M) {
  __shared__ char As[BM * BK * 2];       // 8 KB
  __shared__ char Bs[NOUT * BK * 2];     // 32 KB
  const int tid = threadIdx.x;
  const int lane = tid & 63;
  const int w = tid >> 6;
  const int row0 = blockIdx.x * BM;

  const int arow = tid >> 2;             // 0..63
  const int akoff = (tid & 3) * 16;      // k offset within BK (quads contiguous 256B)
  const bool aval = (row0 + arow) < M;

  f32x4 acc[4][4] = {};

  for (int k0 = 0; k0 < KDIM; k0 += BK) {
    // ---- stage A: fp32 global -> bf16 LDS (XOR-swizzled 16B groups) ----
    {
      const float* gx = X + (size_t)(row0 + arow) * KDIM + k0 + akoff;
      float4 f[4];
#pragma unroll
      for (int i = 0; i < 4; ++i)
        f[i] = aval ? *(const float4*)(gx + i * 4) : make_float4(0.f, 0.f, 0.f, 0.f);
#pragma unroll
      for (int hfl = 0; hfl < 2; ++hfl) {
        uint4 o;
        o.x = pk2bf(f[2 * hfl].x, f[2 * hfl].y);
        o.y = pk2bf(f[2 * hfl].z, f[2 * hfl].w);
        o.z = pk2bf(f[2 * hfl + 1].x, f[2 * hfl + 1].y);
        o.w = pk2bf(f[2 * hfl + 1].z, f[2 * hfl + 1].w);
        int q = (tid & 3) * 2 + hfl;
        int phys = q ^ (arow & 7);
        *(uint4*)(As + (arow * 8 + phys) * 16) = o;
      }
    }
    // ---- stage B: 256x64 bf16 via global_load_lds (L2-resident W) ----
#pragma unroll
    for (int i = 0; i < 8; ++i) {
      int c = i * 256 + tid;
      int row = c >> 3, q = (c & 7) ^ (row & 7);
      const ushort_t* g = Wb + (size_t)row * KDIM + k0 + q * 8;
      GLOAD_LDS16(g, Bs + c * 16);
    }
    __syncthreads();

#pragma unroll
    for (int kk = 0; kk < 2; ++kk) {
      bf16x8 aF[4], bF[4];
      int qq = kk * 4 + (lane >> 4);
#pragma unroll
      for (int rt = 0; rt < 4; ++rt) {
        int r = rt * 16 + (lane & 15);
        int phys = qq ^ (r & 7);
        aF[rt] = *(const bf16x8*)(As + r * 128 + phys * 16);
      }
#pragma unroll
      for (int ct = 0; ct < 4; ++ct) {
        int cl = w * 64 + ct * 16 + (lane & 15);
        int phys = qq ^ (cl & 7);
        bF[ct] = *(const bf16x8*)(Bs + cl * 128 + phys * 16);
      }
#pragma unroll
      for (int rt = 0; rt < 4; ++rt)
#pragma unroll
        for (int ct = 0; ct < 4; ++ct)
          acc[rt][ct] = __builtin_amdgcn_mfma_f32_16x16x32_bf16(aF[rt], bF[ct], acc[rt][ct], 0, 0, 0);
    }
    __syncthreads();
  }

  // ---- fused per-node attention scores; wave w == head w ----
  const int h = w;
  float att_s[4], att_d[4];
#pragma unroll
  for (int ct = 0; ct < 4; ++ct) {
    att_s[ct] = att[h * 2 * CC + ct * 16 + (lane & 15)];
    att_d[ct] = att[h * 2 * CC + CC + ct * 16 + (lane & 15)];
  }
#pragma unroll
  for (int rt = 0; rt < 4; ++rt) {
#pragma unroll
    for (int reg = 0; reg < 4; ++reg) {
      float ls = 0.f, ld_ = 0.f;
#pragma unroll
      for (int ct = 0; ct < 4; ++ct) {
        float a = acc[rt][ct][reg];
        ls += a * att_s[ct];
        ld_ += a * att_d[ct];
      }
#pragma unroll
      for (int off = 1; off < 16; off <<= 1) {
        ls += __shfl_xor(ls, off);
        ld_ += __shfl_xor(ld_, off);
      }
      int r = row0 + rt * 16 + (lane >> 4) * 4 + reg;
      if ((lane & 15) == 0 && r < M) {
        s_src[r * HH + h] = ls;
        s_dst[r * HH + h] = ld_;
      }
    }
  }

  // ---- Wh store (m89 layout: col=lane&15, row=(lane>>4)*4+reg) ----
#pragma unroll
  for (int rt = 0; rt < 4; ++rt) {
#pragma unroll
    for (int reg = 0; reg < 4; ++reg) {
      int r = row0 + rt * 16 + (lane >> 4) * 4 + reg;
      if (r < M) {
#pragma unroll
        for (int ct = 0; ct < 4; ++ct) {
          int ccol = w * 64 + ct * 16 + (lane & 15);
          Wh[(size_t)r * NOUT + ccol] = f2bf(acc[rt][ct][reg]);
        }
      }
    }
  }
}

// ---------------- aggregation: inline p=exp(leaky(.)), 4-deep MLP, fused ELU ----------------
__global__ __launch_bounds__(256)
void aggregate(const ushort_t* __restrict__ Wh, const float* __restrict__ s_src,
               const float* __restrict__ s_dst, const int* __restrict__ row_ptr,
               const int* __restrict__ csr_src, float* __restrict__ out, int N) {
  int wid = (int)((blockIdx.x * 256 + threadIdx.x) >> 6);
  int lane = threadIdx.x & 63;
  if (wid >= N) return;
  int half = lane >> 5, cl = lane & 31;
  int h = cl >> 3;
  int start = row_ptr[wid], end = row_ptr[wid + 1];
  float sd = s_dst[wid * HH + h];
  float acc[8] = {};
  float dsum = 0.f;
  int idx = start + half;
  for (; idx + 6 < end; idx += 8) {
    int s[4];
#pragma unroll
    for (int k = 0; k < 4; ++k) s[k] = csr_src[idx + 2 * k];
    float p[4];
    uint4 wv[4];
#pragma unroll
    for (int k = 0; k < 4; ++k) {
      float v = s_src[s[k] * HH + h] + sd;
      v = v > 0.f ? v : 0.2f * v;
      p[k] = __expf(v);
      wv[k] = *(const uint4*)(Wh + (size_t)s[k] * NOUT + cl * 8);
    }
#pragma unroll
    for (int k = 0; k < 4; ++k) {
      dsum += p[k];
#pragma unroll
      for (int j = 0; j < 4; ++j) {
        unsigned u = ((const unsigned*)&wv[k])[j];
        acc[2 * j]     += p[k] * __uint_as_float(u << 16);
        acc[2 * j + 1] += p[k] * __uint_as_float(u & 0xffff0000u);
      }
    }
  }
  for (; idx < end; idx += 2) {
    int s0 = csr_src[idx];
    float v = s_src[s0 * HH + h] + sd;
    v = v > 0.f ? v : 0.2f * v;
    float p0 = __expf(v);
    uint4 w0 = *(const uint4*)(Wh + (size_t)s0 * NOUT + cl * 8);
    dsum += p0;
#pragma unroll
    for (int j = 0; j < 4; ++j) {
      unsigned u0 = ((const unsigned*)&w0)[j];
      acc[2 * j]     += p0 * __uint_as_float(u0 << 16);
      acc[2 * j + 1] += p0 * __uint_as_float(u0 & 0xffff0000u);
    }
  }
#pragma unroll
  for (int j = 0; j < 8; ++j) acc[j] += __shfl_xor(acc[j], 32);
  dsum += __shfl_xor(dsum, 32);
  if (half == 0) {
    float rd = 1.0f / (dsum + 1e-16f);
    float o[8];
#pragma unroll
    for (int j = 0; j < 8; ++j) {
      float a = acc[j] * rd;
      o[j] = a > 0.f ? a : expm1f(a);
    }
    float* op = out + (size_t)wid * NOUT + cl * 8;
    *(float4*)op = make_float4(o[0], o[1], o[2], o[3]);
    *(float4*)(op + 4) = make_float4(o[4], o[5], o[6], o[7]);
  }
}

extern "C" void kernel_launch(void* const* d_in, const int* in_sizes, int n_in,
                              void* d_out, int out_size, void* d_ws, size_t ws_size,
                              hipStream_t stream) {
  const float* x = (const float*)d_in[0];
  const int* ei = (const int*)d_in[1];
  const float* W = (const float*)d_in[2];
  const float* att = (const float*)d_in[3];
  float* out = (float*)d_out;
  const int N = in_sizes[0] / KDIM;
  const int E = in_sizes[1] / 2;
  const int NPAD = ((N + BM - 1) / BM) * BM;
  const int NB = (N + 255) / 256;

  char* p = (char*)d_ws;
  auto alloc = [&](size_t bytes) {
    char* r = p;
    p += (bytes + 255) & ~(size_t)255;
    return r;
  };
  ushort_t* Wb   = (ushort_t*)alloc((size_t)NOUT * KDIM * 2);
  ushort_t* Wh   = (ushort_t*)alloc((size_t)NPAD * NOUT * 2);
  float* s_src   = (float*)alloc((size_t)N * HH * 4);
  float* s_dst   = (float*)alloc((size_t)N * HH * 4);
  int* deg       = (int*)alloc((size_t)N * 4);
  int* row_ptr   = (int*)alloc((size_t)(N + 1) * 4);
  int* cursor    = (int*)alloc((size_t)N * 4);
  int* bsums     = (int*)alloc(256 * 4);
  int* csr_src   = (int*)alloc((size_t)E * 4);

  (void)hipMemsetAsync(deg, 0, (size_t)N * 4, stream);

  const int wblocks = (NOUT * KDIM) / (256 * 8);  // 32
  int eblocks = (E + 255) / 256;
  deg_convW<<<wblocks + eblocks, 256, 0, stream>>>(W, Wb, ei, deg, wblocks, E);

  scan_partial<<<NB, 256, 0, stream>>>(deg, bsums, N);
  scan_final2<<<NB, 256, 0, stream>>>(deg, bsums, row_ptr, cursor, N, NB);

  csr_scatter<<<eblocks, 256, 0, stream>>>(ei, cursor, csr_src, E);

  gemm_direct<<<NPAD / BM, 256, 0, stream>>>(x, Wb, Wh, s_src, s_dst, att, N);

  aggregate<<<(N + 3) / 4, 256, 0, stream>>>(Wh, s_src, s_dst, row_ptr, csr_src, out, N);
}